// Round 1
// baseline (5478.679 us; speedup 1.0000x reference)
//
#include <hip/hip_runtime.h>

// Wavelet_Convolution: out = relu(phi1 @ (kernel * (phi0 @ (x @ W))))
// N=100000, F=128, NNZ=1.6M per sparse matrix (COO, int32 idx, f32 vals).
//
// ws layout: [0, N*F)        = X_prime (x @ W)
//            [N*F, 2*N*F)    = X_t     (phi0 @ X_prime)
// Requires ws_size >= 2*N*F*4 = 102.4 MB.

constexpr int kN = 100000;
constexpr int kF = 128;
constexpr int kNNZ = 1600000;

// ---------------------------------------------------------------------------
// GEMM: Xp = x @ W.  16 rows/block, 256 threads.
// Thread t: row-group rg = t>>5 (2 rows), float4-col c4 = t&31 (4 cols).
// x rows staged in LDS (broadcast reads), W streamed float4 via L1/L2.
// ---------------------------------------------------------------------------
__global__ __launch_bounds__(256) void gemm_xw(const float* __restrict__ x,
                                               const float* __restrict__ W,
                                               float* __restrict__ Xp) {
    __shared__ float xs[16 * kF];
    const int t = threadIdx.x;
    const size_t rowBase = (size_t)blockIdx.x * 16;

    const float4* x4 = (const float4*)(x + rowBase * kF);
    float4* xs4 = (float4*)xs;
    xs4[t] = x4[t];
    xs4[256 + t] = x4[256 + t];
    __syncthreads();

    const int c4 = t & 31;   // float4 column index (cols c4*4 .. c4*4+3)
    const int rg = t >> 5;   // row group 0..7 -> rows rg*2, rg*2+1
    const float4* W4 = (const float4*)W;
    const float* xr0 = xs + (rg * 2) * kF;
    const float* xr1 = xr0 + kF;

    float4 a0 = make_float4(0.f, 0.f, 0.f, 0.f);
    float4 a1 = make_float4(0.f, 0.f, 0.f, 0.f);
    #pragma unroll 4
    for (int k = 0; k < kF; ++k) {
        const float4 w = W4[k * 32 + c4];
        const float s0 = xr0[k];
        const float s1 = xr1[k];
        a0.x = fmaf(s0, w.x, a0.x);
        a0.y = fmaf(s0, w.y, a0.y);
        a0.z = fmaf(s0, w.z, a0.z);
        a0.w = fmaf(s0, w.w, a0.w);
        a1.x = fmaf(s1, w.x, a1.x);
        a1.y = fmaf(s1, w.y, a1.y);
        a1.z = fmaf(s1, w.z, a1.z);
        a1.w = fmaf(s1, w.w, a1.w);
    }

    float4* o4 = (float4*)(Xp + rowBase * kF);
    o4[(rg * 2 + 0) * 32 + c4] = a0;
    o4[(rg * 2 + 1) * 32 + c4] = a1;
}

// ---------------------------------------------------------------------------
// SpMM scatter: Xout[rows[e]] += vals[e] * (scale ? scale[cols[e]] : 1) * Xin[cols[e]]
// 32 lanes per edge; each lane: float4 gather + 4 f32 atomics.
// ---------------------------------------------------------------------------
template <bool HAS_SCALE>
__global__ __launch_bounds__(256) void spmm_scatter(const int* __restrict__ rows,
                                                    const int* __restrict__ cols,
                                                    const float* __restrict__ vals,
                                                    const float* __restrict__ scale,
                                                    const float* __restrict__ Xin,
                                                    float* __restrict__ Xout) {
    const int tid  = blockIdx.x * 256 + threadIdx.x;
    const int e    = tid >> 5;      // 32 lanes per edge; grid sized exactly
    const int lane = tid & 31;

    const int r = rows[e];
    const int c = cols[e];
    float v = vals[e];
    if (HAS_SCALE) v *= scale[c];

    const float4 xv = ((const float4*)(Xin + (size_t)c * kF))[lane];
    float* dst = Xout + (size_t)r * kF + lane * 4;
    unsafeAtomicAdd(dst + 0, v * xv.x);
    unsafeAtomicAdd(dst + 1, v * xv.y);
    unsafeAtomicAdd(dst + 2, v * xv.z);
    unsafeAtomicAdd(dst + 3, v * xv.w);
}

// ---------------------------------------------------------------------------
// In-place ReLU on d_out (runs after spmm2's atomics have drained).
// ---------------------------------------------------------------------------
__global__ __launch_bounds__(256) void relu_inplace(float* __restrict__ out, int n4) {
    float4* o4 = (float4*)out;
    for (int i = blockIdx.x * 256 + threadIdx.x; i < n4; i += gridDim.x * 256) {
        float4 v = o4[i];
        v.x = fmaxf(v.x, 0.f);
        v.y = fmaxf(v.y, 0.f);
        v.z = fmaxf(v.z, 0.f);
        v.w = fmaxf(v.w, 0.f);
        o4[i] = v;
    }
}

extern "C" void kernel_launch(void* const* d_in, const int* in_sizes, int n_in,
                              void* d_out, int out_size, void* d_ws, size_t ws_size,
                              hipStream_t stream) {
    const float* x    = (const float*)d_in[0];
    const float* W    = (const float*)d_in[1];
    const float* kern = (const float*)d_in[2];
    const int*   p0r  = (const int*)d_in[3];
    const int*   p0c  = (const int*)d_in[4];
    const float* p0v  = (const float*)d_in[5];
    const int*   p1r  = (const int*)d_in[6];
    const int*   p1c  = (const int*)d_in[7];
    const float* p1v  = (const float*)d_in[8];
    float* out = (float*)d_out;

    float* Xp = (float*)d_ws;                  // [N, F]
    float* Xt = Xp + (size_t)kN * kF;          // [N, F]

    const size_t matBytes = sizeof(float) * (size_t)kN * kF;

    // Atomic accumulation targets must start at zero every call.
    hipMemsetAsync(Xt, 0, matBytes, stream);
    hipMemsetAsync(out, 0, matBytes, stream);

    // 1) X' = x @ W
    gemm_xw<<<kN / 16, 256, 0, stream>>>(x, W, Xp);

    // 2) X_t = phi0 @ X'
    const int spmmBlocks = kNNZ * 32 / 256;    // 200000
    spmm_scatter<false><<<spmmBlocks, 256, 0, stream>>>(p0r, p0c, p0v, nullptr, Xp, Xt);

    // 3) out = phi1 @ (kernel * X_t)   (kernel scale folded into edge weight)
    spmm_scatter<true><<<spmmBlocks, 256, 0, stream>>>(p1r, p1c, p1v, kern, Xt, out);

    // 4) relu in place
    const int n4 = kN * kF / 4;
    relu_inplace<<<2048, 256, 0, stream>>>(out, n4);
}

// Round 2
// 720.393 us; speedup vs baseline: 7.6051x; 7.6051x over previous
//
#include <hip/hip_runtime.h>

// Wavelet_Convolution: out = relu(phi1 @ (kernel * (phi0 @ (x @ W))))
// N=100000, F=128, NNZ=1.6M per sparse matrix (COO, int32 idx, f32 vals).
//
// Strategy: device-side counting-sort to CSR per sparse matrix, then
// gather-based SpMM (one 32-lane group per output row, no f32 atomics).
//
// Buffers:
//   d_out : doubles as X' = x@W (gemm output), later overwritten by final out.
//   ws    : [Xt (51.2MB)][row_start][cursor][blockSums][records (12.8MB)]

constexpr int kN = 100000;
constexpr int kF = 128;
constexpr int kNNZ = 1600000;

// Scan geometry: 98 blocks x 256 threads x 4 elements = 100352 >= N+1
constexpr int kScanBlocks = 98;
constexpr int kScanN = kScanBlocks * 1024;  // padded element count

// ---------------------------------------------------------------------------
// GEMM: Xp = x @ W.  16 rows/block, 256 threads.
// ---------------------------------------------------------------------------
__global__ __launch_bounds__(256) void gemm_xw(const float* __restrict__ x,
                                               const float* __restrict__ W,
                                               float* __restrict__ Xp) {
    __shared__ float xs[16 * kF];
    const int t = threadIdx.x;
    const size_t rowBase = (size_t)blockIdx.x * 16;

    const float4* x4 = (const float4*)(x + rowBase * kF);
    float4* xs4 = (float4*)xs;
    xs4[t] = x4[t];
    xs4[256 + t] = x4[256 + t];
    __syncthreads();

    const int c4 = t & 31;
    const int rg = t >> 5;
    const float4* W4 = (const float4*)W;
    const float* xr0 = xs + (rg * 2) * kF;
    const float* xr1 = xr0 + kF;

    float4 a0 = make_float4(0.f, 0.f, 0.f, 0.f);
    float4 a1 = make_float4(0.f, 0.f, 0.f, 0.f);
    #pragma unroll 4
    for (int k = 0; k < kF; ++k) {
        const float4 w = W4[k * 32 + c4];
        const float s0 = xr0[k];
        const float s1 = xr1[k];
        a0.x = fmaf(s0, w.x, a0.x);
        a0.y = fmaf(s0, w.y, a0.y);
        a0.z = fmaf(s0, w.z, a0.z);
        a0.w = fmaf(s0, w.w, a0.w);
        a1.x = fmaf(s1, w.x, a1.x);
        a1.y = fmaf(s1, w.y, a1.y);
        a1.z = fmaf(s1, w.z, a1.z);
        a1.w = fmaf(s1, w.w, a1.w);
    }

    float4* o4 = (float4*)(Xp + rowBase * kF);
    o4[(rg * 2 + 0) * 32 + c4] = a0;
    o4[(rg * 2 + 1) * 32 + c4] = a1;
}

// ---------------------------------------------------------------------------
// CSR build step 1: histogram of row indices (int atomics, L2-resident 400KB).
// ---------------------------------------------------------------------------
__global__ __launch_bounds__(256) void hist_rows(const int* __restrict__ rows,
                                                 int* __restrict__ counts) {
    const int e = blockIdx.x * 256 + threadIdx.x;  // grid sized exactly NNZ/256
    atomicAdd(&counts[rows[e]], 1);
}

// ---------------------------------------------------------------------------
// CSR build step 2a: per-block exclusive scan (1024 elems/block via int4).
// Writes per-block partial scan + block totals.
// ---------------------------------------------------------------------------
__global__ __launch_bounds__(256) void scan_block(const int* __restrict__ in,
                                                  int* __restrict__ partial,
                                                  int* __restrict__ blockSums) {
    const int b = blockIdx.x, t = threadIdx.x;
    int4 v = ((const int4*)in)[b * 256 + t];
    const int s = v.x + v.y + v.z + v.w;

    __shared__ int sm[256];
    sm[t] = s;
    __syncthreads();
    #pragma unroll
    for (int off = 1; off < 256; off <<= 1) {
        const int val = (t >= off) ? sm[t - off] : 0;
        __syncthreads();
        sm[t] += val;
        __syncthreads();
    }
    const int inc = sm[t];
    const int ex = inc - s;
    if (t == 255) blockSums[b] = inc;

    int4 o;
    o.x = ex;
    o.y = ex + v.x;
    o.z = ex + v.x + v.y;
    o.w = ex + v.x + v.y + v.z;
    ((int4*)partial)[b * 256 + t] = o;
}

// ---------------------------------------------------------------------------
// CSR build step 2b: exclusive scan of the (<=256) block sums, single block.
// ---------------------------------------------------------------------------
__global__ __launch_bounds__(256) void scan_sums(int* __restrict__ blockSums, int nb) {
    const int t = threadIdx.x;
    const int v = (t < nb) ? blockSums[t] : 0;
    __shared__ int sm[256];
    sm[t] = v;
    __syncthreads();
    #pragma unroll
    for (int off = 1; off < 256; off <<= 1) {
        const int val = (t >= off) ? sm[t - off] : 0;
        __syncthreads();
        sm[t] += val;
        __syncthreads();
    }
    if (t < nb) blockSums[t] = sm[t] - v;
}

// ---------------------------------------------------------------------------
// CSR build step 2c: add block offsets -> final row_start; also init cursor.
// ---------------------------------------------------------------------------
__global__ __launch_bounds__(256) void scan_add(int* __restrict__ row_start,
                                                int* __restrict__ cursor,
                                                const int* __restrict__ blockSums) {
    const int b = blockIdx.x, t = threadIdx.x;
    const int base = blockSums[b];
    int4 v = ((const int4*)row_start)[b * 256 + t];
    v.x += base; v.y += base; v.z += base; v.w += base;
    ((int4*)row_start)[b * 256 + t] = v;
    ((int4*)cursor)[b * 256 + t] = v;
}

// ---------------------------------------------------------------------------
// CSR build step 3: scatter edges into row-sorted (col,val) 8B records.
// ---------------------------------------------------------------------------
__global__ __launch_bounds__(256) void scatter_edges(const int* __restrict__ rows,
                                                     const int* __restrict__ cols,
                                                     const float* __restrict__ vals,
                                                     int* __restrict__ cursor,
                                                     unsigned long long* __restrict__ rec) {
    const int e = blockIdx.x * 256 + threadIdx.x;  // grid sized exactly NNZ/256
    const int r = rows[e];
    const int pos = atomicAdd(&cursor[r], 1);
    const unsigned long long p =
        ((unsigned long long)__float_as_uint(vals[e]) << 32) | (unsigned int)cols[e];
    rec[pos] = p;
}

// ---------------------------------------------------------------------------
// Gather SpMM: 32 lanes per output row. Each row written exactly once.
// ROW_SCALE: multiply the finished row by scale[r] (fuses "kernel *" into spmm1).
// RELU: fuse final relu (spmm2).
// ---------------------------------------------------------------------------
template <bool ROW_SCALE, bool RELU>
__global__ __launch_bounds__(256) void spmm_csr(const int* __restrict__ row_start,
                                                const unsigned long long* __restrict__ rec,
                                                const float* __restrict__ scale,
                                                const float* __restrict__ Xin,
                                                float* __restrict__ Xout) {
    const int tid = blockIdx.x * 256 + threadIdx.x;
    const int r = tid >> 5;        // grid: N*32/256 = 12500 blocks exactly
    const int lane = tid & 31;

    const int s = row_start[r];
    const int e = row_start[r + 1];

    const float4* Xin4 = (const float4*)Xin;
    float4 acc = make_float4(0.f, 0.f, 0.f, 0.f);
    for (int j = s; j < e; ++j) {
        const unsigned long long p = rec[j];
        const int c = (int)(unsigned int)p;
        const float v = __uint_as_float((unsigned int)(p >> 32));
        const float4 xv = Xin4[(size_t)c * 32 + lane];
        acc.x = fmaf(v, xv.x, acc.x);
        acc.y = fmaf(v, xv.y, acc.y);
        acc.z = fmaf(v, xv.z, acc.z);
        acc.w = fmaf(v, xv.w, acc.w);
    }
    if (ROW_SCALE) {
        const float k = scale[r];
        acc.x *= k; acc.y *= k; acc.z *= k; acc.w *= k;
    }
    if (RELU) {
        acc.x = fmaxf(acc.x, 0.f);
        acc.y = fmaxf(acc.y, 0.f);
        acc.z = fmaxf(acc.z, 0.f);
        acc.w = fmaxf(acc.w, 0.f);
    }
    ((float4*)Xout)[(size_t)r * 32 + lane] = acc;
}

extern "C" void kernel_launch(void* const* d_in, const int* in_sizes, int n_in,
                              void* d_out, int out_size, void* d_ws, size_t ws_size,
                              hipStream_t stream) {
    const float* x    = (const float*)d_in[0];
    const float* W    = (const float*)d_in[1];
    const float* kern = (const float*)d_in[2];
    const int*   p0r  = (const int*)d_in[3];
    const int*   p0c  = (const int*)d_in[4];
    const float* p0v  = (const float*)d_in[5];
    const int*   p1r  = (const int*)d_in[6];
    const int*   p1c  = (const int*)d_in[7];
    const float* p1v  = (const float*)d_in[8];
    float* out = (float*)d_out;                 // doubles as X' before final write

    // ws layout (all 16B-aligned)
    char* w = (char*)d_ws;
    float* Xt = (float*)w;                                   // 51.2 MB
    size_t off = (size_t)kN * kF * sizeof(float);
    int* row_start = (int*)(w + off);  off += (size_t)kScanN * sizeof(int);   // 401,408 B
    int* cursor    = (int*)(w + off);  off += (size_t)kScanN * sizeof(int);   // 401,408 B
    int* blockSums = (int*)(w + off);  off += 1024;
    unsigned long long* rec = (unsigned long long*)(w + off);                 // 12.8 MB

    const int edgeBlocks = kNNZ / 256;     // 6250
    const int rowBlocks  = kN * 32 / 256;  // 12500

    // 1) X' = x @ W  -> d_out
    gemm_xw<<<kN / 16, 256, 0, stream>>>(x, W, out);

    // ---- CSR build for phi0 ----
    hipMemsetAsync(cursor, 0, (size_t)kScanN * sizeof(int), stream);
    hist_rows<<<edgeBlocks, 256, 0, stream>>>(p0r, cursor);
    scan_block<<<kScanBlocks, 256, 0, stream>>>(cursor, row_start, blockSums);
    scan_sums<<<1, 256, 0, stream>>>(blockSums, kScanBlocks);
    scan_add<<<kScanBlocks, 256, 0, stream>>>(row_start, cursor, blockSums);
    scatter_edges<<<edgeBlocks, 256, 0, stream>>>(p0r, p0c, p0v, cursor, rec);

    // 2) Xt = kernel * (phi0 @ X')   (row-scale fused; scales Xt row r by kern[r])
    spmm_csr<true, false><<<rowBlocks, 256, 0, stream>>>(row_start, rec, kern, out, Xt);

    // ---- CSR build for phi1 (reuse scratch) ----
    hipMemsetAsync(cursor, 0, (size_t)kScanN * sizeof(int), stream);
    hist_rows<<<edgeBlocks, 256, 0, stream>>>(p1r, cursor);
    scan_block<<<kScanBlocks, 256, 0, stream>>>(cursor, row_start, blockSums);
    scan_sums<<<1, 256, 0, stream>>>(blockSums, kScanBlocks);
    scan_add<<<kScanBlocks, 256, 0, stream>>>(row_start, cursor, blockSums);
    scatter_edges<<<edgeBlocks, 256, 0, stream>>>(p1r, p1c, p1v, cursor, rec);

    // 3) out = relu(phi1 @ Xt)   (relu fused)
    spmm_csr<false, true><<<rowBlocks, 256, 0, stream>>>(row_start, rec, nullptr, Xt, out);
}

// Round 3
// 634.587 us; speedup vs baseline: 8.6335x; 1.1352x over previous
//
#include <hip/hip_runtime.h>

// Wavelet_Convolution: out = relu(phi1 @ (kernel * (phi0 @ (x @ W))))
// N=100000, F=128, NNZ=1.6M per sparse matrix (COO, int32 idx, f32 vals).
//
// Pipeline: bf16-MFMA GEMM -> merged counting-sort CSR build (both matrices)
//           -> gather SpMM (coalesced rec prefetch + shuffle broadcast).

constexpr int kN = 100000;
constexpr int kF = 128;
constexpr int kNNZ = 1600000;

constexpr int kScanBlocks = 98;              // per matrix: 98*1024 >= N+1
constexpr int kScanN = kScanBlocks * 1024;   // padded bins per matrix
constexpr int kEdgeBlocks = kNNZ / 256;      // 6250

typedef short bf16x8 __attribute__((ext_vector_type(8)));
typedef float f32x4 __attribute__((ext_vector_type(4)));
typedef unsigned short ushort4v __attribute__((ext_vector_type(4)));
typedef unsigned short ushort8v __attribute__((ext_vector_type(8)));

__device__ __forceinline__ unsigned short f32_to_bf16(float f) {
    unsigned int u = __float_as_uint(f);
    u += 0x7fffu + ((u >> 16) & 1u);   // round-to-nearest-even
    return (unsigned short)(u >> 16);
}

// ---------------------------------------------------------------------------
// Pre-kernel: Wt[n][k] = bf16(W[k][n])   (128x128, one-shot transpose+convert)
// ---------------------------------------------------------------------------
__global__ __launch_bounds__(256) void transpose_w(const float* __restrict__ W,
                                                   unsigned short* __restrict__ Wt) {
    const int e = blockIdx.x * 256 + threadIdx.x;   // grid 64 -> 16384 elems
    const int n = e & 127, k = e >> 7;
    Wt[n * 128 + k] = f32_to_bf16(W[e]);            // W[e] == W[k][n]
}

// ---------------------------------------------------------------------------
// GEMM: X' = x @ W via mfma_f32_16x16x32_bf16.
// Block: 256 thr = 4 waves, 64 rows. Wave w owns rows w*16..w*16+15, all 128 cols.
// LDS: xs 64x128 bf16 (16KB), wt 128x128 bf16 (32KB), both XOR-swizzled
// (byte ^= (row&7)<<4, expressed in u16 units as idx ^= (row&7)<<3).
// ---------------------------------------------------------------------------
__global__ __launch_bounds__(256) void gemm_mfma(const float* __restrict__ x,
                                                 const unsigned short* __restrict__ Wt,
                                                 float* __restrict__ Xp) {
    __shared__ __align__(16) unsigned short xs[64 * 128];
    __shared__ __align__(16) unsigned short wt[128 * 128];

    const int t = threadIdx.x;
    const int rowBase = blockIdx.x * 64;

    // --- stage x tile (f32 global -> bf16 LDS, swizzled) ---
    {
        const int lrow = t >> 2;                 // 0..63
        const int q = t & 3;
        int srow = rowBase + lrow;
        if (srow >= kN) srow = kN - 1;           // clamp (stores are guarded)
        const float4* xr = (const float4*)(x + (size_t)srow * kF) + q * 8;
        #pragma unroll
        for (int i = 0; i < 8; ++i) {
            const float4 f = xr[i];
            ushort4v h;
            h.x = f32_to_bf16(f.x); h.y = f32_to_bf16(f.y);
            h.z = f32_to_bf16(f.z); h.w = f32_to_bf16(f.w);
            const int kidx = q * 32 + i * 4;
            *(ushort4v*)&xs[lrow * 128 + (kidx ^ ((lrow & 7) << 3))] = h;
        }
    }
    // --- stage Wt (bf16 global -> LDS, swizzled, coalesced 16B chunks) ---
    {
        const ushort8v* Wt8 = (const ushort8v*)Wt;
        #pragma unroll
        for (int i = 0; i < 8; ++i) {
            const int c = i * 256 + t;           // chunk 0..2047
            const int n = c >> 4;
            const int kb = (c & 15) * 8;
            *(ushort8v*)&wt[n * 128 + (kb ^ ((n & 7) << 3))] = Wt8[c];
        }
    }
    __syncthreads();

    const int w = t >> 6;          // wave 0..3
    const int l = t & 63;          // lane
    const int lr = l & 15;
    const int lq = l >> 4;         // 0..3

    f32x4 acc[8];
    #pragma unroll
    for (int n = 0; n < 8; ++n) acc[n] = (f32x4){0.f, 0.f, 0.f, 0.f};

    const int arow = w * 16 + lr;
    #pragma unroll
    for (int ks = 0; ks < 4; ++ks) {
        const int akidx = ks * 32 + lq * 8;
        const bf16x8 a = *(const bf16x8*)&xs[arow * 128 + (akidx ^ ((arow & 7) << 3))];
        #pragma unroll
        for (int n = 0; n < 8; ++n) {
            const int bn = n * 16 + lr;
            const bf16x8 b = *(const bf16x8*)&wt[bn * 128 + (akidx ^ ((bn & 7) << 3))];
            acc[n] = __builtin_amdgcn_mfma_f32_16x16x32_bf16(a, b, acc[n], 0, 0, 0);
        }
    }

    // C/D layout: col = l&15, row = (l>>4)*4 + j   [m89-verified]
    #pragma unroll
    for (int j = 0; j < 4; ++j) {
        const int row = rowBase + w * 16 + lq * 4 + j;
        if (row < kN) {
            float* orow = Xp + (size_t)row * kF + lr;
            #pragma unroll
            for (int n = 0; n < 8; ++n) orow[n * 16] = acc[n][j];
        }
    }
}

// ---------------------------------------------------------------------------
// CSR build (both matrices in one launch each stage)
// ---------------------------------------------------------------------------
__global__ __launch_bounds__(256) void hist_both(const int* __restrict__ r0,
                                                 const int* __restrict__ r1,
                                                 int* __restrict__ c0,
                                                 int* __restrict__ c1) {
    const int b = blockIdx.x;
    const bool first = b < kEdgeBlocks;
    const int* rows = first ? r0 : r1;
    int* cnt = first ? c0 : c1;
    const int e = (first ? b : b - kEdgeBlocks) * 256 + threadIdx.x;
    atomicAdd(&cnt[rows[e]], 1);
}

__global__ __launch_bounds__(256) void scan_block(const int* __restrict__ in,
                                                  int* __restrict__ partial,
                                                  int* __restrict__ blockSums) {
    const int b = blockIdx.x, t = threadIdx.x;       // grid 196 (both segments)
    int4 v = ((const int4*)in)[b * 256 + t];
    const int s = v.x + v.y + v.z + v.w;

    __shared__ int sm[256];
    sm[t] = s;
    __syncthreads();
    #pragma unroll
    for (int off = 1; off < 256; off <<= 1) {
        const int val = (t >= off) ? sm[t - off] : 0;
        __syncthreads();
        sm[t] += val;
        __syncthreads();
    }
    const int inc = sm[t];
    const int ex = inc - s;
    if (t == 255) blockSums[b] = inc;

    int4 o;
    o.x = ex;
    o.y = ex + v.x;
    o.z = ex + v.x + v.y;
    o.w = ex + v.x + v.y + v.z;
    ((int4*)partial)[b * 256 + t] = o;
}

// Exclusive scan of 196 block sums with a segment reset at index 98.
__global__ __launch_bounds__(256) void scan_sums(int* __restrict__ blockSums) {
    const int t = threadIdx.x;
    const int v = (t < 2 * kScanBlocks) ? blockSums[t] : 0;
    __shared__ int sm[256];
    __shared__ int seg0;
    sm[t] = v;
    __syncthreads();
    #pragma unroll
    for (int off = 1; off < 256; off <<= 1) {
        const int val = (t >= off) ? sm[t - off] : 0;
        __syncthreads();
        sm[t] += val;
        __syncthreads();
    }
    if (t == kScanBlocks - 1) seg0 = sm[t];   // inclusive sum of segment 0
    __syncthreads();
    int ex = sm[t] - v;
    if (t >= kScanBlocks) ex -= seg0;
    if (t < 2 * kScanBlocks) blockSums[t] = ex;
}

__global__ __launch_bounds__(256) void scan_add(int* __restrict__ row_start,
                                                int* __restrict__ cursor,
                                                const int* __restrict__ blockSums) {
    const int b = blockIdx.x, t = threadIdx.x;       // grid 196
    const int base = blockSums[b];
    int4 v = ((const int4*)row_start)[b * 256 + t];
    v.x += base; v.y += base; v.z += base; v.w += base;
    ((int4*)row_start)[b * 256 + t] = v;
    ((int4*)cursor)[b * 256 + t] = v;
}

__global__ __launch_bounds__(256) void scatter_both(
    const int* __restrict__ r0, const int* __restrict__ c0, const float* __restrict__ v0,
    const int* __restrict__ r1, const int* __restrict__ c1, const float* __restrict__ v1,
    int* __restrict__ cur0, int* __restrict__ cur1,
    unsigned long long* __restrict__ rec0, unsigned long long* __restrict__ rec1) {
    const int b = blockIdx.x;
    const bool first = b < kEdgeBlocks;
    const int* rows = first ? r0 : r1;
    const int* cols = first ? c0 : c1;
    const float* vals = first ? v0 : v1;
    int* cursor = first ? cur0 : cur1;
    unsigned long long* rec = first ? rec0 : rec1;

    const int e = (first ? b : b - kEdgeBlocks) * 256 + threadIdx.x;
    const int r = rows[e];
    const int pos = atomicAdd(&cursor[r], 1);
    rec[pos] = ((unsigned long long)__float_as_uint(vals[e]) << 32) | (unsigned int)cols[e];
}

// ---------------------------------------------------------------------------
// Gather SpMM: 32 lanes per row. Coalesced rec load per 32-edge chunk,
// shuffle-broadcast, 4-wide unrolled gather (4 dwordx4 loads in flight).
// ---------------------------------------------------------------------------
template <bool ROW_SCALE, bool RELU>
__global__ __launch_bounds__(256) void spmm_csr(const int* __restrict__ row_start,
                                                const unsigned long long* __restrict__ rec,
                                                const float* __restrict__ scale,
                                                const float* __restrict__ Xin,
                                                float* __restrict__ Xout) {
    const int tid = blockIdx.x * 256 + threadIdx.x;
    const int r = tid >> 5;          // grid = kN*32/256 exactly
    const int lane = tid & 31;

    const int s = row_start[r];
    const int e = row_start[r + 1];

    const float4* Xin4 = (const float4*)Xin;
    float4 acc = make_float4(0.f, 0.f, 0.f, 0.f);

    for (int base = s; base < e; base += 32) {
        int cl = 0;
        float vl = 0.f;
        if (base + lane < e) {
            const unsigned long long p = rec[base + lane];
            cl = (int)(unsigned int)p;
            vl = __uint_as_float((unsigned int)(p >> 32));
        }
        const int m4 = (min(32, e - base) + 3) & ~3;
        for (int j = 0; j < m4; j += 4) {
            const int c0 = __shfl(cl, j, 32);
            const int c1 = __shfl(cl, j + 1, 32);
            const int c2 = __shfl(cl, j + 2, 32);
            const int c3 = __shfl(cl, j + 3, 32);
            const float w0 = __shfl(vl, j, 32);
            const float w1 = __shfl(vl, j + 1, 32);
            const float w2 = __shfl(vl, j + 2, 32);
            const float w3 = __shfl(vl, j + 3, 32);
            const float4 x0 = Xin4[(size_t)c0 * 32 + lane];
            const float4 x1 = Xin4[(size_t)c1 * 32 + lane];
            const float4 x2 = Xin4[(size_t)c2 * 32 + lane];
            const float4 x3 = Xin4[(size_t)c3 * 32 + lane];
            acc.x = fmaf(w0, x0.x, acc.x); acc.y = fmaf(w0, x0.y, acc.y);
            acc.z = fmaf(w0, x0.z, acc.z); acc.w = fmaf(w0, x0.w, acc.w);
            acc.x = fmaf(w1, x1.x, acc.x); acc.y = fmaf(w1, x1.y, acc.y);
            acc.z = fmaf(w1, x1.z, acc.z); acc.w = fmaf(w1, x1.w, acc.w);
            acc.x = fmaf(w2, x2.x, acc.x); acc.y = fmaf(w2, x2.y, acc.y);
            acc.z = fmaf(w2, x2.z, acc.z); acc.w = fmaf(w2, x2.w, acc.w);
            acc.x = fmaf(w3, x3.x, acc.x); acc.y = fmaf(w3, x3.y, acc.y);
            acc.z = fmaf(w3, x3.z, acc.z); acc.w = fmaf(w3, x3.w, acc.w);
        }
    }
    if (ROW_SCALE) {
        const float k = scale[r];
        acc.x *= k; acc.y *= k; acc.z *= k; acc.w *= k;
    }
    if (RELU) {
        acc.x = fmaxf(acc.x, 0.f); acc.y = fmaxf(acc.y, 0.f);
        acc.z = fmaxf(acc.z, 0.f); acc.w = fmaxf(acc.w, 0.f);
    }
    ((float4*)Xout)[(size_t)r * 32 + lane] = acc;
}

extern "C" void kernel_launch(void* const* d_in, const int* in_sizes, int n_in,
                              void* d_out, int out_size, void* d_ws, size_t ws_size,
                              hipStream_t stream) {
    const float* x    = (const float*)d_in[0];
    const float* W    = (const float*)d_in[1];
    const float* kern = (const float*)d_in[2];
    const int*   p0r  = (const int*)d_in[3];
    const int*   p0c  = (const int*)d_in[4];
    const float* p0v  = (const float*)d_in[5];
    const int*   p1r  = (const int*)d_in[6];
    const int*   p1c  = (const int*)d_in[7];
    const float* p1v  = (const float*)d_in[8];
    float* out = (float*)d_out;                // doubles as X' before final write

    // ws layout (16B-aligned slabs)
    char* w = (char*)d_ws;
    size_t off = 0;
    float* Xt = (float*)(w + off);             off += (size_t)kN * kF * 4;   // 51.2 MB
    unsigned short* Wt = (unsigned short*)(w + off); off += 128 * 128 * 2;   // 32 KB
    int* row_start0 = (int*)(w + off);         off += (size_t)kScanN * 4;
    int* row_start1 = (int*)(w + off);         off += (size_t)kScanN * 4;
    int* cursor0 = (int*)(w + off);            off += (size_t)kScanN * 4;
    int* cursor1 = (int*)(w + off);            off += (size_t)kScanN * 4;
    int* blockSums = (int*)(w + off);          off += 1024;
    unsigned long long* rec0 = (unsigned long long*)(w + off); off += (size_t)kNNZ * 8;
    unsigned long long* rec1 = (unsigned long long*)(w + off); off += (size_t)kNNZ * 8;

    const int rowBlocks = kN * 32 / 256;       // 12500

    // 1) X' = x @ W  -> d_out   (bf16 MFMA)
    transpose_w<<<64, 256, 0, stream>>>(W, Wt);
    gemm_mfma<<<(kN + 63) / 64, 256, 0, stream>>>(x, Wt, out);

    // 2) CSR build for both matrices (merged stages)
    hipMemsetAsync(cursor0, 0, (size_t)2 * kScanN * 4, stream);
    hist_both<<<2 * kEdgeBlocks, 256, 0, stream>>>(p0r, p1r, cursor0, cursor1);
    scan_block<<<2 * kScanBlocks, 256, 0, stream>>>(cursor0, row_start0, blockSums);
    scan_sums<<<1, 256, 0, stream>>>(blockSums);
    scan_add<<<2 * kScanBlocks, 256, 0, stream>>>(row_start0, cursor0, blockSums);
    scatter_both<<<2 * kEdgeBlocks, 256, 0, stream>>>(p0r, p0c, p0v, p1r, p1c, p1v,
                                                      cursor0, cursor1, rec0, rec1);

    // 3) Xt = kernel * (phi0 @ X')
    spmm_csr<true, false><<<rowBlocks, 256, 0, stream>>>(row_start0, rec0, kern, out, Xt);

    // 4) out = relu(phi1 @ Xt)
    spmm_csr<false, true><<<rowBlocks, 256, 0, stream>>>(row_start1, rec1, nullptr, Xt, out);
}